// Round 1
// baseline (419.607 us; speedup 1.0000x reference)
//
#include <hip/hip_runtime.h>
#include <hip/hip_bf16.h>

#define N_  100000
#define F_  5
#define D_  128
#define H_  4
#define HD_ 32
#define E_  800000
#define NT_ 32

typedef __attribute__((ext_vector_type(8))) short bf16x8;
typedef __attribute__((ext_vector_type(4))) float f32x4;

__device__ __forceinline__ unsigned short f2bf(float f) {
  unsigned u = __float_as_uint(f);
  u += 0x7FFF + ((u >> 16) & 1);          // round-to-nearest-even
  return (unsigned short)(u >> 16);
}

__device__ __forceinline__ unsigned pk2(float a, float b) {
  __hip_bfloat162 h = __float22bfloat162_rn(make_float2(a, b));  // v_cvt_pk_bf16_f32
  return *(unsigned*)&h;
}

__device__ __forceinline__ float2 bf2f2(unsigned u) {
  float2 r;
  r.x = __uint_as_float(u << 16);
  r.y = __uint_as_float(u & 0xffff0000u);
  return r;
}

// ---------------------------------------------------------------------------
// Weight pre-pass: W[k][m] (fp32) -> fragment-tiled bf16 WT.
// All 9 weight matrices converted in ONE dispatch (dst offsets contiguous).
// ---------------------------------------------------------------------------
template<int K, int M>
__device__ __forceinline__ void wconv_one(const float* __restrict__ W,
                                          unsigned short* __restrict__ WT,
                                          int idx) {
  const int r = idx & 7;
  const int l = (idx >> 3) & 15;
  const int rest = idx >> 7;
  const int kq = rest % (K / 8);
  const int i  = rest / (K / 8);
  WT[idx] = f2bf(W[(kq * 8 + r) * M + i * 16 + l]);
}

__global__ __launch_bounds__(256) void k_wconv_all(
    const float* __restrict__ w0, const float* __restrict__ w1,
    const float* __restrict__ w2, const float* __restrict__ w3,
    const float* __restrict__ w4, const float* __restrict__ w5,
    const float* __restrict__ w6, const float* __restrict__ w7,
    const float* __restrict__ w8, unsigned short* __restrict__ WT)
{
  const int idx = blockIdx.x * 256 + threadIdx.x;
  // segment table (element offsets into WT):
  //   p2 [0,8192) 64x128 | p3 [8192,24576) | q [24576,40960) | k [40960,57344)
  //   v [57344,73728) | s [73728,90112) | u1 [90112,98304) 128x64
  //   u2 [98304,106496) 64x128 | u3 [106496,122880)
  if (idx < 8192)        wconv_one<64, 128>(w0, WT,          idx);
  else if (idx < 24576)  wconv_one<128,128>(w1, WT + 8192,   idx - 8192);
  else if (idx < 40960)  wconv_one<128,128>(w2, WT + 24576,  idx - 24576);
  else if (idx < 57344)  wconv_one<128,128>(w3, WT + 40960,  idx - 40960);
  else if (idx < 73728)  wconv_one<128,128>(w4, WT + 57344,  idx - 57344);
  else if (idx < 90112)  wconv_one<128,128>(w5, WT + 73728,  idx - 73728);
  else if (idx < 98304)  wconv_one<128, 64>(w6, WT + 90112,  idx - 90112);
  else if (idx < 106496) wconv_one<64, 128>(w7, WT + 98304,  idx - 98304);
  else                   wconv_one<128,128>(w8, WT + 106496, idx - 106496);
}

// ---------------------------------------------------------------------------
// MFMA GEMM over NW weight sets sharing one LDS-staged X tile.
// INBF: input tensor already bf16 (pure copy staging). OMASK bit ws: output
// stored bf16 (else fp32). RES only used with fp32 output.
// ---------------------------------------------------------------------------
template<int K, int M, int NW, bool RELU, bool RES, bool INBF, int OMASK>
__global__ __launch_bounds__(256) void mfma_gemmN(
    const void* __restrict__ Xv,
    const unsigned short* __restrict__ wt0, const unsigned short* __restrict__ wt1,
    const unsigned short* __restrict__ wt2, const unsigned short* __restrict__ wt3,
    const float* __restrict__ b0, const float* __restrict__ b1,
    const float* __restrict__ b2, const float* __restrict__ b3,
    const float* __restrict__ Res,
    void* __restrict__ y0, void* __restrict__ y1,
    void* __restrict__ y2, void* __restrict__ y3)
{
  constexpr int SX = K + 8;      // LDS row stride (bf16)
  constexpr int IF = M / 32;     // feature tiles per wave (4 or 2)

  __shared__ unsigned short sX[128 * SX];

  const int t = threadIdx.x;
  const int node0 = blockIdx.x * 128;
  const int lane = t & 63;
  const int w  = t >> 6;
  const int wr = w >> 1, wc = w & 1;
  const int l16 = lane & 15, kg = lane >> 4;

  // ---- stage X tile into bf16 LDS ----
  if constexpr (INBF) {
    const unsigned short* X = (const unsigned short*)Xv;
    constexpr int CPR = K / 8;   // 16B chunks per row
    #pragma unroll
    for (int i = 0; i < (128 * CPR) / 256; ++i) {
      const int g = t + 256 * i;
      const int row = g / CPR, c = g % CPR;
      const int node = node0 + row;
      uint4 v = make_uint4(0u, 0u, 0u, 0u);
      if (node < N_) v = *(const uint4*)&X[(long)node * K + c * 8];
      *(uint4*)&sX[row * SX + c * 8] = v;
    }
  } else {
    const float* X = (const float*)Xv;
    #pragma unroll
    for (int i = 0; i < (128 * K / 4) / 256; ++i) {
      const int g = t + 256 * i;
      const int row = g / (K / 4);
      const int kc  = g % (K / 4);
      const int node = node0 + row;
      float4 xv = (node < N_) ? ((const float4*)X)[(long)node * (K / 4) + kc]
                              : make_float4(0.f, 0.f, 0.f, 0.f);
      uint2 p;
      p.x = pk2(xv.x, xv.y);
      p.y = pk2(xv.z, xv.w);
      *(uint2*)&sX[row * SX + kc * 4] = p;
    }
  }
  __syncthreads();

  const unsigned short* wts[4] = {wt0, wt1, wt2, wt3};
  const float* bs[4] = {b0, b1, b2, b3};
  void* ys[4] = {y0, y1, y2, y3};

  #pragma unroll
  for (int ws = 0; ws < NW; ++ws) {
    const unsigned short* __restrict__ WT = wts[ws];

    f32x4 acc[IF][4];
    #pragma unroll
    for (int i = 0; i < IF; ++i)
      #pragma unroll
      for (int j = 0; j < 4; ++j) acc[i][j] = (f32x4){0.f, 0.f, 0.f, 0.f};

    #pragma unroll
    for (int k0 = 0; k0 < K; k0 += 32) {
      const int kq = k0 / 8 + kg;
      bf16x8 aw[IF];
      #pragma unroll
      for (int i = 0; i < IF; ++i) {
        const int ti = wr * IF + i;
        aw[i] = *(const bf16x8*)&WT[((ti * (K / 8) + kq) * 16 + l16) * 8];
      }
      #pragma unroll
      for (int j = 0; j < 4; ++j) {
        const bf16x8 bx = *(const bf16x8*)&sX[(wc * 64 + j * 16 + l16) * SX + k0 + kg * 8];
        #pragma unroll
        for (int i = 0; i < IF; ++i)
          acc[i][j] = __builtin_amdgcn_mfma_f32_16x16x32_bf16(aw[i], bx, acc[i][j], 0, 0, 0);
      }
    }

    // ---- epilogue ----
    const float* __restrict__ bias = bs[ws];
    const bool obf = (OMASK >> ws) & 1;
    float4 b4[IF];
    #pragma unroll
    for (int i = 0; i < IF; ++i)
      b4[i] = *(const float4*)&bias[(wr * IF + i) * 16 + kg * 4];

    #pragma unroll
    for (int j = 0; j < 4; ++j) {
      const int node = node0 + wc * 64 + j * 16 + l16;
      if (node >= N_) continue;
      #pragma unroll
      for (int i = 0; i < IF; ++i) {
        const int f0 = (wr * IF + i) * 16 + kg * 4;
        float4 o = make_float4(acc[i][j][0] + b4[i].x, acc[i][j][1] + b4[i].y,
                               acc[i][j][2] + b4[i].z, acc[i][j][3] + b4[i].w);
        if constexpr (RELU) {
          o.x = fmaxf(o.x, 0.f); o.y = fmaxf(o.y, 0.f);
          o.z = fmaxf(o.z, 0.f); o.w = fmaxf(o.w, 0.f);
        }
        if (obf) {
          unsigned short* Yb = (unsigned short*)ys[ws];
          uint2 ob;
          ob.x = pk2(o.x, o.y);
          ob.y = pk2(o.z, o.w);
          *(uint2*)&Yb[(long)node * M + f0] = ob;
        } else {
          float* Yf = (float*)ys[ws];
          if constexpr (RES) {
            const float4 r = *(const float4*)&Res[(long)node * M + f0];
            o.x += r.x; o.y += r.y; o.z += r.z; o.w += r.w;
          }
          *(float4*)&Yf[(long)node * M + f0] = o;
        }
      }
    }
  }
}

// ---------------------------------------------------------------------------
// Small-K GEMM (K=5), fp32 in -> bf16 out.
// ---------------------------------------------------------------------------
template<int K, int M, bool RELU>
__global__ __launch_bounds__(128) void gemm_small(
    const float* __restrict__ X, const float* __restrict__ W,
    const float* __restrict__ bias, unsigned short* __restrict__ Y)
{
  constexpr int FG  = M / 4;
  constexpr int NG  = 128 / FG;
  constexpr int NPT = NT_ / NG;

  __shared__ float sxT[K * 33];
  __shared__ float sw[K * M];
  __shared__ float sb[M];

  const int t = threadIdx.x;
  const long node0 = (long)blockIdx.x * NT_;

  for (int i = t; i < NT_ * K; i += 128) {
    int n = i / K, k = i % K;
    sxT[k * 33 + n] = X[(node0 + n) * K + k];
  }
  for (int i = t; i < K * M; i += 128) sw[i] = W[i];
  if (t < M) sb[t] = bias[t];
  __syncthreads();

  const int tf = t % FG;
  const int tn = t / FG;
  float acc[NPT][4];
  #pragma unroll
  for (int n = 0; n < NPT; ++n)
    #pragma unroll
    for (int f = 0; f < 4; ++f) acc[n][f] = sb[tf * 4 + f];

  #pragma unroll
  for (int j = 0; j < K; ++j) {
    const float4 wv = *(const float4*)&sw[j * M + tf * 4];
    #pragma unroll
    for (int n = 0; n < NPT; ++n) {
      const float xv = sxT[j * 33 + tn * NPT + n];
      acc[n][0] = fmaf(xv, wv.x, acc[n][0]);
      acc[n][1] = fmaf(xv, wv.y, acc[n][1]);
      acc[n][2] = fmaf(xv, wv.z, acc[n][2]);
      acc[n][3] = fmaf(xv, wv.w, acc[n][3]);
    }
  }

  #pragma unroll
  for (int n = 0; n < NPT; ++n) {
    const long row = node0 + tn * NPT + n;
    float ox = acc[n][0], oy = acc[n][1], oz = acc[n][2], ow = acc[n][3];
    if constexpr (RELU) {
      ox = fmaxf(ox, 0.f); oy = fmaxf(oy, 0.f);
      oz = fmaxf(oz, 0.f); ow = fmaxf(ow, 0.f);
    }
    uint2 o;
    o.x = pk2(ox, oy);
    o.y = pk2(oz, ow);
    *(uint2*)&Y[row * M + tf * 4] = o;
  }
}

// ---------------------------------------------------------------------------
// CSR build: histogram -> hierarchical scan -> fill
// ---------------------------------------------------------------------------
#define SCAN_NB ((N_ + 255) / 256)   // 391

__global__ __launch_bounds__(256) void k_zero(int* __restrict__ deg) {
  int i = blockIdx.x * 256 + threadIdx.x;
  if (i < N_) deg[i] = 0;
}

__global__ __launch_bounds__(256) void k_hist(const int* __restrict__ ei,
                                              int* __restrict__ deg) {
  int e = blockIdx.x * 256 + threadIdx.x;
  if (e < E_) atomicAdd(&deg[ei[E_ + e]], 1);
}

__global__ __launch_bounds__(256) void k_scan1(const int* __restrict__ deg,
                                               int* __restrict__ off,
                                               int* __restrict__ bsum) {
  __shared__ int s[256];
  const int t = threadIdx.x;
  const int i = blockIdx.x * 256 + t;
  const int v = (i < N_) ? deg[i] : 0;
  s[t] = v;
  __syncthreads();
  #pragma unroll
  for (int o = 1; o < 256; o <<= 1) {
    int u = (t >= o) ? s[t - o] : 0;
    __syncthreads();
    s[t] += u;
    __syncthreads();
  }
  if (i < N_) off[i] = s[t] - v;
  if (t == 255) bsum[blockIdx.x] = s[255];
}

__global__ __launch_bounds__(512) void k_scan2(int* __restrict__ bsum) {
  __shared__ int s[512];
  const int t = threadIdx.x;
  const int v = (t < SCAN_NB) ? bsum[t] : 0;
  s[t] = v;
  __syncthreads();
  #pragma unroll
  for (int o = 1; o < 512; o <<= 1) {
    int u = (t >= o) ? s[t - o] : 0;
    __syncthreads();
    s[t] += u;
    __syncthreads();
  }
  if (t < SCAN_NB) bsum[t] = s[t] - v;
}

__global__ __launch_bounds__(256) void k_scan3(int* __restrict__ off,
                                               const int* __restrict__ bsum,
                                               int* __restrict__ cur) {
  const int i = blockIdx.x * 256 + threadIdx.x;
  if (i < N_) {
    const int o = off[i] + bsum[blockIdx.x];
    off[i] = o;
    cur[i] = o;
  }
}

__global__ __launch_bounds__(256) void k_fill(const int* __restrict__ ei,
                                              int* __restrict__ cur,
                                              int* __restrict__ esrc) {
  int e = blockIdx.x * 256 + threadIdx.x;
  if (e < E_) {
    int src = ei[e], dst = ei[E_ + e];
    int pos = atomicAdd(&cur[dst], 1);
    esrc[pos] = src;
  }
}

// ---------------------------------------------------------------------------
// Flash-style attention aggregation (bf16 q/k/v): one wave per destination
// node. Lane owns channels 2*lane, 2*lane+1 -> head = lane>>4; score reduce
// is 4 shfl_xor steps within 16-lane groups. Unrolled by 2.
// ---------------------------------------------------------------------------
__global__ __launch_bounds__(256) void k_attn(
    const int* __restrict__ esrc, const int* __restrict__ off,
    const int* __restrict__ deg,
    const unsigned short* __restrict__ q,
    const unsigned short* __restrict__ kbuf,
    const unsigned short* __restrict__ vbuf,
    float* __restrict__ out)
{
  const int node = blockIdx.x * 4 + (threadIdx.x >> 6);
  const int lane = threadIdx.x & 63;
  if (node >= N_) return;

  const int start = off[node];
  const int cnt   = deg[node];
  const float scale = 0.17677669529663687f;  // 1/sqrt(32)

  const float2 qv = bf2f2(*(const unsigned*)&q[(long)node * D_ + 2 * lane]);
  const float qx = qv.x * scale, qy = qv.y * scale;

  float m = -__builtin_inff(), l = 0.f, a0 = 0.f, a1 = 0.f;

  int i = start;
  const int end = start + cnt;

  for (; i + 1 < end; i += 2) {
    const int sa = esrc[i];
    const int sb = esrc[i + 1];
    const unsigned kua = *(const unsigned*)&kbuf[(long)sa * D_ + 2 * lane];
    const unsigned kub = *(const unsigned*)&kbuf[(long)sb * D_ + 2 * lane];
    const unsigned vua = *(const unsigned*)&vbuf[(long)sa * D_ + 2 * lane];
    const unsigned vub = *(const unsigned*)&vbuf[(long)sb * D_ + 2 * lane];

    const float2 ka = bf2f2(kua);
    const float2 kb = bf2f2(kub);
    float pa = qx * ka.x + qy * ka.y;
    float pb = qx * kb.x + qy * kb.y;
    #pragma unroll
    for (int msk = 8; msk >= 1; msk >>= 1) {
      pa += __shfl_xor(pa, msk);
      pb += __shfl_xor(pb, msk);
    }

    const float2 va = bf2f2(vua);
    const float2 vb = bf2f2(vub);
    const float mn = fmaxf(m, fmaxf(pa, pb));
    const float s  = __expf(m - mn);
    const float ea = __expf(pa - mn);
    const float eb = __expf(pb - mn);
    l  = l * s + ea + eb;
    a0 = a0 * s + ea * va.x + eb * vb.x;
    a1 = a1 * s + ea * va.y + eb * vb.y;
    m = mn;
  }

  if (i < end) {
    const int src = esrc[i];
    const unsigned ku = *(const unsigned*)&kbuf[(long)src * D_ + 2 * lane];
    const unsigned vu = *(const unsigned*)&vbuf[(long)src * D_ + 2 * lane];
    const float2 kf = bf2f2(ku);
    float p = qx * kf.x + qy * kf.y;
    #pragma unroll
    for (int msk = 8; msk >= 1; msk >>= 1) p += __shfl_xor(p, msk);

    const float2 vf = bf2f2(vu);
    const float mn = fmaxf(m, p);
    const float s  = __expf(m - mn);
    const float e  = __expf(p - mn);
    l  = l * s + e;
    a0 = a0 * s + e * vf.x;
    a1 = a1 * s + e * vf.y;
    m = mn;
  }

  const float r0 = (l > 0.f) ? a0 / l : 0.f;
  const float r1 = (l > 0.f) ? a1 / l : 0.f;
  float2* op = (float2*)&out[(long)node * D_ + 2 * lane];
  float2 cv = *op;
  cv.x += r0;
  cv.y += r1;
  *op = cv;
}

// ---------------------------------------------------------------------------
extern "C" void kernel_launch(void* const* d_in, const int* in_sizes, int n_in,
                              void* d_out, int out_size, void* d_ws, size_t ws_size,
                              hipStream_t stream) {
  const float* x   = (const float*)d_in[0];
  const int*   ei  = (const int*)d_in[1];
  const float* pW1 = (const float*)d_in[2];  const float* pb1 = (const float*)d_in[3];
  const float* pW2 = (const float*)d_in[4];  const float* pb2 = (const float*)d_in[5];
  const float* pW3 = (const float*)d_in[6];  const float* pb3 = (const float*)d_in[7];
  const float* uW1 = (const float*)d_in[8];  const float* ub1 = (const float*)d_in[9];
  const float* uW2 = (const float*)d_in[10]; const float* ub2 = (const float*)d_in[11];
  const float* uW3 = (const float*)d_in[12]; const float* ub3 = (const float*)d_in[13];
  const float* qW  = (const float*)d_in[14]; const float* qb  = (const float*)d_in[15];
  const float* kW  = (const float*)d_in[16]; const float* kb  = (const float*)d_in[17];
  const float* vW  = (const float*)d_in[18]; const float* vb  = (const float*)d_in[19];
  const float* sW  = (const float*)d_in[20]; const float* sb  = (const float*)d_in[21];

  float* out = (float*)d_out;
  float* ws  = (float*)d_ws;

  const long ND = (long)N_ * D_;
  // regions (each ND floats): 0=h_init(bf16)+CSR overlay, 1=q, 2=k, 3=v
  unsigned short* h16 = (unsigned short*)ws;
  unsigned short* q16 = (unsigned short*)(ws + ND);
  unsigned short* k16 = (unsigned short*)(ws + 2 * ND);
  unsigned short* v16 = (unsigned short*)(ws + 3 * ND);

  // bf16 fragment-tiled weights (region 4, ~246 KB)
  unsigned short* wtb = (unsigned short*)(ws + 4 * ND);
  unsigned short* wt_p2 = wtb;            // 64x128
  unsigned short* wt_p3 = wtb + 8192;     // 128x128
  unsigned short* wt_q  = wtb + 24576;
  unsigned short* wt_k  = wtb + 40960;
  unsigned short* wt_v  = wtb + 57344;
  unsigned short* wt_s  = wtb + 73728;
  unsigned short* wt_u1 = wtb + 90112;    // 128x64
  unsigned short* wt_u2 = wtb + 98304;    // 64x128
  unsigned short* wt_u3 = wtb + 106496;   // 128x128

  // CSR overlays in region 0 (h16 dead after the fused projections)
  int* deg  = (int*)ws;
  int* off  = deg + N_;
  int* cur  = off + N_;
  int* esrc = cur + N_;
  int* bsum = esrc + E_;

  // MLP temporaries (regions 1/2 reused: dead before q/k written, dead after attn)
  unsigned short* t1b = k16;
  unsigned short* t2b = q16;

  const int g32 = N_ / NT_;            // 3125
  const int gT  = (N_ + 127) / 128;    // 782

  // --- weight pre-pass (bf16, fragment-tiled): ONE dispatch for all 9 ---
  k_wconv_all<<<480, 256, 0, stream>>>(pW2, pW3, qW, kW, vW, sW, uW1, uW2, uW3, wtb);

  // --- prep MLP: x -> h16 ---
  gemm_small<F_, 64, true><<<g32, 128, 0, stream>>>(x, pW1, pb1, t1b);
  mfma_gemmN<64, 128, 1, true,  false, true, 1><<<gT, 256, 0, stream>>>(
      t1b, wt_p2, nullptr, nullptr, nullptr, pb2, nullptr, nullptr, nullptr,
      nullptr, t2b, nullptr, nullptr, nullptr);
  mfma_gemmN<128, 128, 1, false, false, true, 1><<<gT, 256, 0, stream>>>(
      t2b, wt_p3, nullptr, nullptr, nullptr, pb3, nullptr, nullptr, nullptr,
      nullptr, h16, nullptr, nullptr, nullptr);

  // --- fused projections: h16 -> q,k,v (bf16) + skip (fp32, into out) ---
  mfma_gemmN<128, 128, 4, false, false, true, 0b0111><<<gT, 256, 0, stream>>>(
      h16, wt_q, wt_k, wt_v, wt_s, qb, kb, vb, sb,
      nullptr, q16, k16, v16, out);

  // --- CSR build (region 0 now free) ---
  k_zero <<<(N_ + 255) / 256, 256, 0, stream>>>(deg);
  k_hist <<<(E_ + 255) / 256, 256, 0, stream>>>(ei, deg);
  k_scan1<<<SCAN_NB, 256, 0, stream>>>(deg, off, bsum);
  k_scan2<<<1, 512, 0, stream>>>(bsum);
  k_scan3<<<SCAN_NB, 256, 0, stream>>>(off, bsum, cur);
  k_fill <<<(E_ + 255) / 256, 256, 0, stream>>>(ei, cur, esrc);

  // --- attention (adds onto skip already in out) ---
  k_attn<<<(N_ + 3) / 4, 256, 0, stream>>>(esrc, off, deg, q16, k16, v16, out);

  // --- update MLP with residual: out = h + mlp(h), h == out ---
  mfma_gemmN<128, 64, 1, true,  false, false, 1><<<gT, 256, 0, stream>>>(
      out, wt_u1, nullptr, nullptr, nullptr, ub1, nullptr, nullptr, nullptr,
      nullptr, t1b, nullptr, nullptr, nullptr);
  mfma_gemmN<64, 128, 1, true,  false, true, 1><<<gT, 256, 0, stream>>>(
      t1b, wt_u2, nullptr, nullptr, nullptr, ub2, nullptr, nullptr, nullptr,
      nullptr, t2b, nullptr, nullptr, nullptr);
  mfma_gemmN<128, 128, 1, false, true, true, 0><<<gT, 256, 0, stream>>>(
      t2b, wt_u3, nullptr, nullptr, nullptr, ub3, nullptr, nullptr, nullptr,
      out, out, nullptr, nullptr, nullptr);
}

// Round 2
// 372.070 us; speedup vs baseline: 1.1278x; 1.1278x over previous
//
#include <hip/hip_runtime.h>
#include <hip/hip_bf16.h>

#define N_  100000
#define F_  5
#define D_  128
#define H_  4
#define HD_ 32
#define E_  800000

typedef __attribute__((ext_vector_type(8))) short bf16x8;
typedef __attribute__((ext_vector_type(4))) float f32x4;

__device__ __forceinline__ unsigned short f2bf(float f) {
  unsigned u = __float_as_uint(f);
  u += 0x7FFF + ((u >> 16) & 1);          // round-to-nearest-even
  return (unsigned short)(u >> 16);
}

__device__ __forceinline__ unsigned pk2(float a, float b) {
  __hip_bfloat162 h = __float22bfloat162_rn(make_float2(a, b));  // v_cvt_pk_bf16_f32
  return *(unsigned*)&h;
}

__device__ __forceinline__ float2 bf2f2(unsigned u) {
  float2 r;
  r.x = __uint_as_float(u << 16);
  r.y = __uint_as_float(u & 0xffff0000u);
  return r;
}

// DPP rotate-reduce: sum across each 16-lane row (head group), result in all lanes.
__device__ __forceinline__ float rowsum16(float x) {
  x += __int_as_float(__builtin_amdgcn_update_dpp(0, __float_as_int(x), 0x128, 0xF, 0xF, false)); // row_ror:8
  x += __int_as_float(__builtin_amdgcn_update_dpp(0, __float_as_int(x), 0x124, 0xF, 0xF, false)); // row_ror:4
  x += __int_as_float(__builtin_amdgcn_update_dpp(0, __float_as_int(x), 0x122, 0xF, 0xF, false)); // row_ror:2
  x += __int_as_float(__builtin_amdgcn_update_dpp(0, __float_as_int(x), 0x121, 0xF, 0xF, false)); // row_ror:1
  return x;
}

// ---------------------------------------------------------------------------
// Weight pre-pass: W[k][m] (fp32) -> fragment-tiled bf16 WT. One dispatch for
// all 9 weights; extra blocks zero the degree histogram.
// ---------------------------------------------------------------------------
template<int K, int M>
__device__ __forceinline__ void wconv_one(const float* __restrict__ W,
                                          unsigned short* __restrict__ WT,
                                          int idx) {
  const int r = idx & 7;
  const int l = (idx >> 3) & 15;
  const int rest = idx >> 7;
  const int kq = rest % (K / 8);
  const int i  = rest / (K / 8);
  WT[idx] = f2bf(W[(kq * 8 + r) * M + i * 16 + l]);
}

#define WCONV_NB 480   // 122880 elements / 256
#define SCAN_NB ((N_ + 255) / 256)   // 391

__global__ __launch_bounds__(256) void k_wconv_all(
    const float* __restrict__ w0, const float* __restrict__ w1,
    const float* __restrict__ w2, const float* __restrict__ w3,
    const float* __restrict__ w4, const float* __restrict__ w5,
    const float* __restrict__ w6, const float* __restrict__ w7,
    const float* __restrict__ w8, unsigned short* __restrict__ WT,
    int* __restrict__ deg)
{
  if (blockIdx.x >= WCONV_NB) {
    const int i = (blockIdx.x - WCONV_NB) * 256 + threadIdx.x;
    if (i < N_) deg[i] = 0;
    return;
  }
  const int idx = blockIdx.x * 256 + threadIdx.x;
  if (idx < 8192)        wconv_one<64, 128>(w0, WT,          idx);
  else if (idx < 24576)  wconv_one<128,128>(w1, WT + 8192,   idx - 8192);
  else if (idx < 40960)  wconv_one<128,128>(w2, WT + 24576,  idx - 24576);
  else if (idx < 57344)  wconv_one<128,128>(w3, WT + 40960,  idx - 40960);
  else if (idx < 73728)  wconv_one<128,128>(w4, WT + 57344,  idx - 57344);
  else if (idx < 90112)  wconv_one<128,128>(w5, WT + 73728,  idx - 73728);
  else if (idx < 98304)  wconv_one<128, 64>(w6, WT + 90112,  idx - 90112);
  else if (idx < 106496) wconv_one<64, 128>(w7, WT + 98304,  idx - 98304);
  else                   wconv_one<128,128>(w8, WT + 106496, idx - 106496);
}

// ---------------------------------------------------------------------------
// Shared GEMM fragments: LDS-staged X tile (rows=nodes, cols=K features,
// stride K+8) x fragment-tiled global weights -> acc[M/32][4].
// ---------------------------------------------------------------------------
template<int K, int M>
__device__ __forceinline__ void gemm_frag(const unsigned short* sX,
                                          const unsigned short* __restrict__ WT,
                                          f32x4 (*acc)[4],
                                          int wr, int wc, int l16, int kg)
{
  constexpr int SX = K + 8;
  constexpr int IF = M / 32;
  #pragma unroll
  for (int i = 0; i < IF; ++i)
    #pragma unroll
    for (int j = 0; j < 4; ++j) acc[i][j] = (f32x4){0.f, 0.f, 0.f, 0.f};
  #pragma unroll
  for (int k0 = 0; k0 < K; k0 += 32) {
    const int kq = k0 / 8 + kg;
    bf16x8 aw[IF];
    #pragma unroll
    for (int i = 0; i < IF; ++i)
      aw[i] = *(const bf16x8*)&WT[(((wr * IF + i) * (K / 8) + kq) * 16 + l16) * 8];
    #pragma unroll
    for (int j = 0; j < 4; ++j) {
      const bf16x8 bx = *(const bf16x8*)&sX[(wc * 64 + j * 16 + l16) * SX + k0 + kg * 8];
      #pragma unroll
      for (int i = 0; i < IF; ++i)
        acc[i][j] = __builtin_amdgcn_mfma_f32_16x16x32_bf16(aw[i], bx, acc[i][j], 0, 0, 0);
    }
  }
}

// acc (+bias, opt relu) -> bf16 LDS tile with row stride SXO
template<int M, bool RELU, int SXO>
__device__ __forceinline__ void acc_to_lds(unsigned short* sY, f32x4 (*acc)[4],
                                           const float* __restrict__ bias,
                                           int wr, int wc, int l16, int kg)
{
  constexpr int IF = M / 32;
  float4 b4[IF];
  #pragma unroll
  for (int i = 0; i < IF; ++i)
    b4[i] = *(const float4*)&bias[(wr * IF + i) * 16 + kg * 4];
  #pragma unroll
  for (int j = 0; j < 4; ++j) {
    const int row = wc * 64 + j * 16 + l16;
    #pragma unroll
    for (int i = 0; i < IF; ++i) {
      const int f0 = (wr * IF + i) * 16 + kg * 4;
      float ox = acc[i][j][0] + b4[i].x, oy = acc[i][j][1] + b4[i].y;
      float oz = acc[i][j][2] + b4[i].z, ow = acc[i][j][3] + b4[i].w;
      if constexpr (RELU) {
        ox = fmaxf(ox, 0.f); oy = fmaxf(oy, 0.f);
        oz = fmaxf(oz, 0.f); ow = fmaxf(ow, 0.f);
      }
      uint2 p;
      p.x = pk2(ox, oy);
      p.y = pk2(oz, ow);
      *(uint2*)&sY[row * SXO + f0] = p;
    }
  }
}

// ---------------------------------------------------------------------------
// Fused prep MLP + q/k/v/skip projections. One 128-node tile per block;
// every intermediate lives in LDS (no t1b/t2b/h16 global round trips).
// ---------------------------------------------------------------------------
__global__ __launch_bounds__(256) void k_prep_proj(
    const float* __restrict__ x,
    const float* __restrict__ pW1, const float* __restrict__ pb1,
    const unsigned short* __restrict__ wt_p2, const float* __restrict__ pb2,
    const unsigned short* __restrict__ wt_p3, const float* __restrict__ pb3,
    const unsigned short* __restrict__ wt_q, const float* __restrict__ qb,
    const unsigned short* __restrict__ wt_k, const float* __restrict__ kb,
    const unsigned short* __restrict__ wt_v, const float* __restrict__ vb,
    const unsigned short* __restrict__ wt_s, const float* __restrict__ sb,
    unsigned short* __restrict__ q16, unsigned short* __restrict__ k16,
    unsigned short* __restrict__ v16, float* __restrict__ out)
{
  __shared__ __align__(16) unsigned short bufA[128 * 72];    // 64-ch tiles
  __shared__ __align__(16) unsigned short bufB[128 * 136];   // 128-ch tiles

  const int t = threadIdx.x;
  const int node0 = blockIdx.x * 128;
  const int lane = t & 63;
  const int w  = t >> 6;
  const int wr = w >> 1, wc = w & 1;
  const int l16 = lane & 15, kg = lane >> 4;

  // ---- stage x (5ch fp32) + W1/b1 into bufB head (dead space pre-t2) ----
  float* sxs = (float*)bufB;          // 640 floats
  float* sw1 = (float*)bufB + 640;    // 320 floats (W1) + 64 (b1) contiguous
  {
    const long gbase = (long)node0 * F_;
    for (int i = t; i < 128 * F_; i += 256) {
      const long g = gbase + i;
      sxs[i] = (g < (long)N_ * F_) ? x[g] : 0.f;
    }
    for (int i = t; i < 384; i += 256)
      sw1[i] = (i < 320) ? pW1[i] : pb1[i - 320];
  }
  __syncthreads();

  // ---- stage1: t1 = relu(x@W1+b1) -> bufA (VALU, K=5) ----
  {
    const int n = t >> 1;
    const int half = (t & 1) * 32;
    float xr[F_];
    #pragma unroll
    for (int k = 0; k < F_; ++k) xr[k] = sxs[n * F_ + k];
    const float* sb1 = sw1 + 320;
    #pragma unroll
    for (int q = 0; q < 8; ++q) {
      float o[4];
      #pragma unroll
      for (int jj = 0; jj < 4; ++jj) {
        const int f = half + q * 4 + jj;
        float a = sb1[f];
        #pragma unroll
        for (int k = 0; k < F_; ++k) a = fmaf(xr[k], sw1[k * 64 + f], a);
        o[jj] = fmaxf(a, 0.f);
      }
      uint2 pkd;
      pkd.x = pk2(o[0], o[1]);
      pkd.y = pk2(o[2], o[3]);
      *(uint2*)&bufA[n * 72 + half + q * 4] = pkd;
    }
  }
  __syncthreads();

  f32x4 acc[4][4];

  // ---- stage2: t2 = relu(t1@W2+b2) : K=64 -> M=128, result to bufB ----
  gemm_frag<64, 128>(bufA, wt_p2, acc, wr, wc, l16, kg);
  acc_to_lds<128, true, 136>(bufB, acc, pb2, wr, wc, l16, kg);  // sxs dead
  __syncthreads();

  // ---- stage3: h = t2@W3+b3 : K=128 -> M=128, overwrite bufB ----
  gemm_frag<128, 128>(bufB, wt_p3, acc, wr, wc, l16, kg);
  __syncthreads();                      // all reads of t2 complete
  acc_to_lds<128, false, 136>(bufB, acc, pb3, wr, wc, l16, kg);
  __syncthreads();

  // ---- projections: q,k,v (bf16) ----
  {
    const unsigned short* wtsP[3] = {wt_q, wt_k, wt_v};
    const float* bsP[3] = {qb, kb, vb};
    unsigned short* ysP[3] = {q16, k16, v16};
    #pragma unroll
    for (int ws = 0; ws < 3; ++ws) {
      gemm_frag<128, 128>(bufB, wtsP[ws], acc, wr, wc, l16, kg);
      const float* __restrict__ bias = bsP[ws];
      unsigned short* __restrict__ Yb = ysP[ws];
      float4 b4[4];
      #pragma unroll
      for (int i = 0; i < 4; ++i)
        b4[i] = *(const float4*)&bias[(wr * 4 + i) * 16 + kg * 4];
      #pragma unroll
      for (int j = 0; j < 4; ++j) {
        const int node = node0 + wc * 64 + j * 16 + l16;
        if (node >= N_) continue;
        #pragma unroll
        for (int i = 0; i < 4; ++i) {
          const int f0 = (wr * 4 + i) * 16 + kg * 4;
          uint2 ob;
          ob.x = pk2(acc[i][j][0] + b4[i].x, acc[i][j][1] + b4[i].y);
          ob.y = pk2(acc[i][j][2] + b4[i].z, acc[i][j][3] + b4[i].w);
          *(uint2*)&Yb[(long)node * D_ + f0] = ob;
        }
      }
    }
  }

  // ---- skip projection (fp32 into out) ----
  gemm_frag<128, 128>(bufB, wt_s, acc, wr, wc, l16, kg);
  {
    float4 b4[4];
    #pragma unroll
    for (int i = 0; i < 4; ++i)
      b4[i] = *(const float4*)&sb[(wr * 4 + i) * 16 + kg * 4];
    #pragma unroll
    for (int j = 0; j < 4; ++j) {
      const int node = node0 + wc * 64 + j * 16 + l16;
      if (node >= N_) continue;
      #pragma unroll
      for (int i = 0; i < 4; ++i) {
        const int f0 = (wr * 4 + i) * 16 + kg * 4;
        float4 o = make_float4(acc[i][j][0] + b4[i].x, acc[i][j][1] + b4[i].y,
                               acc[i][j][2] + b4[i].z, acc[i][j][3] + b4[i].w);
        *(float4*)&out[(long)node * D_ + f0] = o;
      }
    }
  }
}

// ---------------------------------------------------------------------------
// Fused update MLP with residual: out = out + mlp(out). Intermediates in LDS.
// ---------------------------------------------------------------------------
__global__ __launch_bounds__(256) void k_update(
    const unsigned short* __restrict__ wt_u1, const float* __restrict__ ub1,
    const unsigned short* __restrict__ wt_u2, const float* __restrict__ ub2,
    const unsigned short* __restrict__ wt_u3, const float* __restrict__ ub3,
    float* __restrict__ out)
{
  __shared__ __align__(16) unsigned short bufA[128 * 72];
  __shared__ __align__(16) unsigned short bufB[128 * 136];

  const int t = threadIdx.x;
  const int node0 = blockIdx.x * 128;
  const int lane = t & 63;
  const int w  = t >> 6;
  const int wr = w >> 1, wc = w & 1;
  const int l16 = lane & 15, kg = lane >> 4;

  // ---- stage h (fp32 out) -> bf16 bufB ----
  #pragma unroll
  for (int i = 0; i < 16; ++i) {
    const int g = t + 256 * i;
    const int row = g >> 5;          // 32 float4 per row
    const int kc  = g & 31;
    const int node = node0 + row;
    float4 xv = (node < N_) ? ((const float4*)out)[(long)node * 32 + kc]
                            : make_float4(0.f, 0.f, 0.f, 0.f);
    uint2 p;
    p.x = pk2(xv.x, xv.y);
    p.y = pk2(xv.z, xv.w);
    *(uint2*)&bufB[row * 136 + kc * 4] = p;
  }
  __syncthreads();

  f32x4 acc[4][4];

  // ---- u1: K=128 -> M=64, relu, to bufA ----
  gemm_frag<128, 64>(bufB, wt_u1, acc, wr, wc, l16, kg);
  acc_to_lds<64, true, 72>(bufA, acc, ub1, wr, wc, l16, kg);
  __syncthreads();                     // also guarantees all u1 reads of bufB done

  // ---- u2: K=64 -> M=128, relu, to bufB ----
  gemm_frag<64, 128>(bufA, wt_u2, acc, wr, wc, l16, kg);
  acc_to_lds<128, true, 136>(bufB, acc, ub2, wr, wc, l16, kg);
  __syncthreads();

  // ---- u3: K=128 -> M=128 + bias + residual(out) -> out ----
  gemm_frag<128, 128>(bufB, wt_u3, acc, wr, wc, l16, kg);
  {
    float4 b4[4];
    #pragma unroll
    for (int i = 0; i < 4; ++i)
      b4[i] = *(const float4*)&ub3[(wr * 4 + i) * 16 + kg * 4];
    #pragma unroll
    for (int j = 0; j < 4; ++j) {
      const int node = node0 + wc * 64 + j * 16 + l16;
      if (node >= N_) continue;
      #pragma unroll
      for (int i = 0; i < 4; ++i) {
        const int f0 = (wr * 4 + i) * 16 + kg * 4;
        const float4 r = *(const float4*)&out[(long)node * D_ + f0];
        float4 o = make_float4(acc[i][j][0] + b4[i].x + r.x,
                               acc[i][j][1] + b4[i].y + r.y,
                               acc[i][j][2] + b4[i].z + r.z,
                               acc[i][j][3] + b4[i].w + r.w);
        *(float4*)&out[(long)node * D_ + f0] = o;
      }
    }
  }
}

// ---------------------------------------------------------------------------
// CSR build: histogram -> hierarchical scan -> fill
// ---------------------------------------------------------------------------
__global__ __launch_bounds__(256) void k_hist(const int* __restrict__ ei,
                                              int* __restrict__ deg) {
  int e = blockIdx.x * 256 + threadIdx.x;
  if (e < E_) atomicAdd(&deg[ei[E_ + e]], 1);
}

__global__ __launch_bounds__(256) void k_scan1(const int* __restrict__ deg,
                                               int* __restrict__ off,
                                               int* __restrict__ bsum) {
  __shared__ int s[256];
  const int t = threadIdx.x;
  const int i = blockIdx.x * 256 + t;
  const int v = (i < N_) ? deg[i] : 0;
  s[t] = v;
  __syncthreads();
  #pragma unroll
  for (int o = 1; o < 256; o <<= 1) {
    int u = (t >= o) ? s[t - o] : 0;
    __syncthreads();
    s[t] += u;
    __syncthreads();
  }
  if (i < N_) off[i] = s[t] - v;
  if (t == 255) bsum[blockIdx.x] = s[255];
}

__global__ __launch_bounds__(512) void k_scan2(int* __restrict__ bsum) {
  __shared__ int s[512];
  const int t = threadIdx.x;
  const int v = (t < SCAN_NB) ? bsum[t] : 0;
  s[t] = v;
  __syncthreads();
  #pragma unroll
  for (int o = 1; o < 512; o <<= 1) {
    int u = (t >= o) ? s[t - o] : 0;
    __syncthreads();
    s[t] += u;
    __syncthreads();
  }
  if (t < SCAN_NB) bsum[t] = s[t] - v;
}

__global__ __launch_bounds__(256) void k_scan3(int* __restrict__ off,
                                               const int* __restrict__ bsum,
                                               int* __restrict__ cur) {
  const int i = blockIdx.x * 256 + threadIdx.x;
  if (i < N_) {
    const int o = off[i] + bsum[blockIdx.x];
    off[i] = o;
    cur[i] = o;
  }
}

__global__ __launch_bounds__(256) void k_fill(const int* __restrict__ ei,
                                              int* __restrict__ cur,
                                              int* __restrict__ esrc) {
  int e = blockIdx.x * 256 + threadIdx.x;
  if (e < E_) {
    int src = ei[e], dst = ei[E_ + e];
    int pos = atomicAdd(&cur[dst], 1);
    esrc[pos] = src;
  }
}

// ---------------------------------------------------------------------------
// Flash-style attention aggregation: one wave per destination node.
// DPP row_ror rotate-reduce over 16-lane head groups (no ds_swizzle chain),
// exp2-domain online softmax (log2e folded into q prescale), 1-pair
// software-pipelined gather.
// ---------------------------------------------------------------------------
__global__ __launch_bounds__(256) void k_attn(
    const int* __restrict__ esrc, const int* __restrict__ off,
    const int* __restrict__ deg,
    const unsigned short* __restrict__ q,
    const unsigned short* __restrict__ kbuf,
    const unsigned short* __restrict__ vbuf,
    float* __restrict__ out)
{
  const int node = blockIdx.x * 4 + (threadIdx.x >> 6);
  const int lane = threadIdx.x & 63;
  if (node >= N_) return;

  const int start = off[node];
  const int cnt   = deg[node];
  // scale * log2(e): scores land directly in exp2 domain
  const float C = 0.17677669529663687f * 1.4426950408889634f;

  const float2 qv = bf2f2(*(const unsigned*)&q[(long)node * D_ + 2 * lane]);
  const float qx = qv.x * C, qy = qv.y * C;

  float m = -__builtin_inff(), l = 0.f, a0 = 0.f, a1 = 0.f;

  const int pairs = cnt >> 1;
  if (pairs > 0) {
    int sa = esrc[start], sb = esrc[start + 1];
    unsigned kua = *(const unsigned*)&kbuf[(long)sa * D_ + 2 * lane];
    unsigned kub = *(const unsigned*)&kbuf[(long)sb * D_ + 2 * lane];
    unsigned vua = *(const unsigned*)&vbuf[(long)sa * D_ + 2 * lane];
    unsigned vub = *(const unsigned*)&vbuf[(long)sb * D_ + 2 * lane];

    for (int p = 1; ; ++p) {
      const unsigned cka = kua, ckb = kub, cva = vua, cvb = vub;
      const bool more = p < pairs;
      if (more) {                          // issue next pair's gathers early
        const int i = start + 2 * p;
        sa = esrc[i];
        sb = esrc[i + 1];
        kua = *(const unsigned*)&kbuf[(long)sa * D_ + 2 * lane];
        kub = *(const unsigned*)&kbuf[(long)sb * D_ + 2 * lane];
        vua = *(const unsigned*)&vbuf[(long)sa * D_ + 2 * lane];
        vub = *(const unsigned*)&vbuf[(long)sb * D_ + 2 * lane];
      }

      const float2 ka = bf2f2(cka);
      const float2 kb2 = bf2f2(ckb);
      float pa = qx * ka.x + qy * ka.y;
      float pb = qx * kb2.x + qy * kb2.y;
      pa = rowsum16(pa);
      pb = rowsum16(pb);

      const float2 va = bf2f2(cva);
      const float2 vb2 = bf2f2(cvb);
      const float mn = fmaxf(m, fmaxf(pa, pb));
      const float s  = __builtin_amdgcn_exp2f(m - mn);
      const float ea = __builtin_amdgcn_exp2f(pa - mn);
      const float eb = __builtin_amdgcn_exp2f(pb - mn);
      l  = fmaf(l, s, ea + eb);
      a0 = fmaf(a0, s, fmaf(ea, va.x, eb * vb2.x));
      a1 = fmaf(a1, s, fmaf(ea, va.y, eb * vb2.y));
      m = mn;

      if (!more) break;
    }
  }

  if (cnt & 1) {
    const int i = start + (cnt & ~1);
    const int src = esrc[i];
    const unsigned ku = *(const unsigned*)&kbuf[(long)src * D_ + 2 * lane];
    const unsigned vu = *(const unsigned*)&vbuf[(long)src * D_ + 2 * lane];
    const float2 kf = bf2f2(ku);
    float p = qx * kf.x + qy * kf.y;
    p = rowsum16(p);

    const float2 vf = bf2f2(vu);
    const float mn = fmaxf(m, p);
    const float s  = __builtin_amdgcn_exp2f(m - mn);
    const float e  = __builtin_amdgcn_exp2f(p - mn);
    l  = fmaf(l, s, e);
    a0 = fmaf(a0, s, e * vf.x);
    a1 = fmaf(a1, s, e * vf.y);
    m = mn;
  }

  const float inv = (l > 0.f) ? (1.0f / l) : 0.f;
  float2* op = (float2*)&out[(long)node * D_ + 2 * lane];
  float2 cv = *op;
  cv.x += a0 * inv;
  cv.y += a1 * inv;
  *op = cv;
}

// ---------------------------------------------------------------------------
extern "C" void kernel_launch(void* const* d_in, const int* in_sizes, int n_in,
                              void* d_out, int out_size, void* d_ws, size_t ws_size,
                              hipStream_t stream) {
  const float* x   = (const float*)d_in[0];
  const int*   ei  = (const int*)d_in[1];
  const float* pW1 = (const float*)d_in[2];  const float* pb1 = (const float*)d_in[3];
  const float* pW2 = (const float*)d_in[4];  const float* pb2 = (const float*)d_in[5];
  const float* pW3 = (const float*)d_in[6];  const float* pb3 = (const float*)d_in[7];
  const float* uW1 = (const float*)d_in[8];  const float* ub1 = (const float*)d_in[9];
  const float* uW2 = (const float*)d_in[10]; const float* ub2 = (const float*)d_in[11];
  const float* uW3 = (const float*)d_in[12]; const float* ub3 = (const float*)d_in[13];
  const float* qW  = (const float*)d_in[14]; const float* qb  = (const float*)d_in[15];
  const float* kW  = (const float*)d_in[16]; const float* kb  = (const float*)d_in[17];
  const float* vW  = (const float*)d_in[18]; const float* vb  = (const float*)d_in[19];
  const float* sW  = (const float*)d_in[20]; const float* sb  = (const float*)d_in[21];

  float* out = (float*)d_out;
  float* ws  = (float*)d_ws;

  const long ND = (long)N_ * D_;
  // regions (ND floats each): 0=CSR overlay, 1=q, 2=k, 3=v; 4=weights
  unsigned short* q16 = (unsigned short*)(ws + ND);
  unsigned short* k16 = (unsigned short*)(ws + 2 * ND);
  unsigned short* v16 = (unsigned short*)(ws + 3 * ND);

  unsigned short* wtb = (unsigned short*)(ws + 4 * ND);
  unsigned short* wt_p2 = wtb;            // 64x128
  unsigned short* wt_p3 = wtb + 8192;     // 128x128
  unsigned short* wt_q  = wtb + 24576;
  unsigned short* wt_k  = wtb + 40960;
  unsigned short* wt_v  = wtb + 57344;
  unsigned short* wt_s  = wtb + 73728;
  unsigned short* wt_u1 = wtb + 90112;    // 128x64
  unsigned short* wt_u2 = wtb + 98304;    // 64x128
  unsigned short* wt_u3 = wtb + 106496;   // 128x128

  // CSR overlays in region 0
  int* deg  = (int*)ws;
  int* off  = deg + N_;
  int* cur  = off + N_;
  int* esrc = cur + N_;
  int* bsum = esrc + E_;

  const int gT = (N_ + 127) / 128;    // 782

  // --- weight conversion + deg zeroing (one dispatch) ---
  k_wconv_all<<<WCONV_NB + SCAN_NB, 256, 0, stream>>>(
      pW2, pW3, qW, kW, vW, sW, uW1, uW2, uW3, wtb, deg);

  // --- CSR build ---
  k_hist <<<(E_ + 255) / 256, 256, 0, stream>>>(ei, deg);
  k_scan1<<<SCAN_NB, 256, 0, stream>>>(deg, off, bsum);
  k_scan2<<<1, 512, 0, stream>>>(bsum);
  k_scan3<<<SCAN_NB, 256, 0, stream>>>(off, bsum, cur);
  k_fill <<<(E_ + 255) / 256, 256, 0, stream>>>(ei, cur, esrc);

  // --- fused prep MLP + projections: x -> q,k,v (bf16) + skip (fp32 in out) ---
  k_prep_proj<<<gT, 256, 0, stream>>>(
      x, pW1, pb1, wt_p2, pb2, wt_p3, pb3,
      wt_q, qb, wt_k, kb, wt_v, vb, wt_s, sb,
      q16, k16, v16, out);

  // --- attention (adds onto skip already in out) ---
  k_attn<<<(N_ + 3) / 4, 256, 0, stream>>>(esrc, off, deg, q16, k16, v16, out);

  // --- fused update MLP with residual: out = out + mlp(out) ---
  k_update<<<gT, 256, 0, stream>>>(wt_u1, ub1, wt_u2, ub2, wt_u3, ub3, out);
}

// Round 3
// 357.778 us; speedup vs baseline: 1.1728x; 1.0399x over previous
//
#include <hip/hip_runtime.h>
#include <hip/hip_bf16.h>

#define N_  100000
#define F_  5
#define D_  128
#define H_  4
#define HD_ 32
#define E_  800000

typedef __attribute__((ext_vector_type(8))) short bf16x8;
typedef __attribute__((ext_vector_type(4))) float f32x4;

__device__ __forceinline__ unsigned short f2bf(float f) {
  unsigned u = __float_as_uint(f);
  u += 0x7FFF + ((u >> 16) & 1);          // round-to-nearest-even
  return (unsigned short)(u >> 16);
}

__device__ __forceinline__ unsigned pk2(float a, float b) {
  __hip_bfloat162 h = __float22bfloat162_rn(make_float2(a, b));  // v_cvt_pk_bf16_f32
  return *(unsigned*)&h;
}

__device__ __forceinline__ float2 bf2f2(unsigned u) {
  float2 r;
  r.x = __uint_as_float(u << 16);
  r.y = __uint_as_float(u & 0xffff0000u);
  return r;
}

// Sum across each 8-lane group (head group when lane owns 4 channels).
// quad_perm xor1, xor2, then row_half_mirror (= xor7 within each 8).
__device__ __forceinline__ float rowsum8(float x) {
  x += __int_as_float(__builtin_amdgcn_update_dpp(0, __float_as_int(x), 0x0B1, 0xF, 0xF, false)); // quad_perm [1,0,3,2]
  x += __int_as_float(__builtin_amdgcn_update_dpp(0, __float_as_int(x), 0x04E, 0xF, 0xF, false)); // quad_perm [2,3,0,1]
  x += __int_as_float(__builtin_amdgcn_update_dpp(0, __float_as_int(x), 0x141, 0xF, 0xF, false)); // row_half_mirror
  return x;
}

// ---------------------------------------------------------------------------
// Weight pre-pass: W[k][m] (fp32) -> fragment-tiled bf16 WT. One dispatch for
// all 9 weights; extra blocks zero the degree histogram.
// ---------------------------------------------------------------------------
template<int K, int M>
__device__ __forceinline__ void wconv_one(const float* __restrict__ W,
                                          unsigned short* __restrict__ WT,
                                          int idx) {
  const int r = idx & 7;
  const int l = (idx >> 3) & 15;
  const int rest = idx >> 7;
  const int kq = rest % (K / 8);
  const int i  = rest / (K / 8);
  WT[idx] = f2bf(W[(kq * 8 + r) * M + i * 16 + l]);
}

#define WCONV_NB 480   // 122880 elements / 256
#define SCAN_NB ((N_ + 255) / 256)   // 391

__global__ __launch_bounds__(256) void k_wconv_all(
    const float* __restrict__ w0, const float* __restrict__ w1,
    const float* __restrict__ w2, const float* __restrict__ w3,
    const float* __restrict__ w4, const float* __restrict__ w5,
    const float* __restrict__ w6, const float* __restrict__ w7,
    const float* __restrict__ w8, unsigned short* __restrict__ WT,
    int* __restrict__ deg)
{
  if (blockIdx.x >= WCONV_NB) {
    const int i = (blockIdx.x - WCONV_NB) * 256 + threadIdx.x;
    if (i < N_) deg[i] = 0;
    return;
  }
  const int idx = blockIdx.x * 256 + threadIdx.x;
  if (idx < 8192)        wconv_one<64, 128>(w0, WT,          idx);
  else if (idx < 24576)  wconv_one<128,128>(w1, WT + 8192,   idx - 8192);
  else if (idx < 40960)  wconv_one<128,128>(w2, WT + 24576,  idx - 24576);
  else if (idx < 57344)  wconv_one<128,128>(w3, WT + 40960,  idx - 40960);
  else if (idx < 73728)  wconv_one<128,128>(w4, WT + 57344,  idx - 57344);
  else if (idx < 90112)  wconv_one<128,128>(w5, WT + 73728,  idx - 73728);
  else if (idx < 98304)  wconv_one<128, 64>(w6, WT + 90112,  idx - 90112);
  else if (idx < 106496) wconv_one<64, 128>(w7, WT + 98304,  idx - 98304);
  else                   wconv_one<128,128>(w8, WT + 106496, idx - 106496);
}

// ---------------------------------------------------------------------------
// Shared GEMM fragments: LDS-staged X tile (rows=nodes, cols=K features,
// stride K+8) x fragment-tiled global weights -> acc[M/32][4].
// ---------------------------------------------------------------------------
template<int K, int M>
__device__ __forceinline__ void gemm_frag(const unsigned short* sX,
                                          const unsigned short* __restrict__ WT,
                                          f32x4 (*acc)[4],
                                          int wr, int wc, int l16, int kg)
{
  constexpr int SX = K + 8;
  constexpr int IF = M / 32;
  #pragma unroll
  for (int i = 0; i < IF; ++i)
    #pragma unroll
    for (int j = 0; j < 4; ++j) acc[i][j] = (f32x4){0.f, 0.f, 0.f, 0.f};
  #pragma unroll
  for (int k0 = 0; k0 < K; k0 += 32) {
    const int kq = k0 / 8 + kg;
    bf16x8 aw[IF];
    #pragma unroll
    for (int i = 0; i < IF; ++i)
      aw[i] = *(const bf16x8*)&WT[(((wr * IF + i) * (K / 8) + kq) * 16 + l16) * 8];
    #pragma unroll
    for (int j = 0; j < 4; ++j) {
      const bf16x8 bx = *(const bf16x8*)&sX[(wc * 64 + j * 16 + l16) * SX + k0 + kg * 8];
      #pragma unroll
      for (int i = 0; i < IF; ++i)
        acc[i][j] = __builtin_amdgcn_mfma_f32_16x16x32_bf16(aw[i], bx, acc[i][j], 0, 0, 0);
    }
  }
}

// acc (+bias, opt relu) -> bf16 LDS tile with row stride SXO
template<int M, bool RELU, int SXO>
__device__ __forceinline__ void acc_to_lds(unsigned short* sY, f32x4 (*acc)[4],
                                           const float* __restrict__ bias,
                                           int wr, int wc, int l16, int kg)
{
  constexpr int IF = M / 32;
  float4 b4[IF];
  #pragma unroll
  for (int i = 0; i < IF; ++i)
    b4[i] = *(const float4*)&bias[(wr * IF + i) * 16 + kg * 4];
  #pragma unroll
  for (int j = 0; j < 4; ++j) {
    const int row = wc * 64 + j * 16 + l16;
    #pragma unroll
    for (int i = 0; i < IF; ++i) {
      const int f0 = (wr * IF + i) * 16 + kg * 4;
      float ox = acc[i][j][0] + b4[i].x, oy = acc[i][j][1] + b4[i].y;
      float oz = acc[i][j][2] + b4[i].z, ow = acc[i][j][3] + b4[i].w;
      if constexpr (RELU) {
        ox = fmaxf(ox, 0.f); oy = fmaxf(oy, 0.f);
        oz = fmaxf(oz, 0.f); ow = fmaxf(ow, 0.f);
      }
      uint2 p;
      p.x = pk2(ox, oy);
      p.y = pk2(oz, ow);
      *(uint2*)&sY[row * SXO + f0] = p;
    }
  }
}

// ---------------------------------------------------------------------------
// Fused prep MLP + q/k/v/skip projections. One 128-node tile per block;
// every intermediate lives in LDS.
// ---------------------------------------------------------------------------
__global__ __launch_bounds__(256) void k_prep_proj(
    const float* __restrict__ x,
    const float* __restrict__ pW1, const float* __restrict__ pb1,
    const unsigned short* __restrict__ wt_p2, const float* __restrict__ pb2,
    const unsigned short* __restrict__ wt_p3, const float* __restrict__ pb3,
    const unsigned short* __restrict__ wt_q, const float* __restrict__ qb,
    const unsigned short* __restrict__ wt_k, const float* __restrict__ kb,
    const unsigned short* __restrict__ wt_v, const float* __restrict__ vb,
    const unsigned short* __restrict__ wt_s, const float* __restrict__ sb,
    unsigned short* __restrict__ q16, unsigned short* __restrict__ k16,
    unsigned short* __restrict__ v16, float* __restrict__ out)
{
  __shared__ __align__(16) unsigned short bufA[128 * 72];    // 64-ch tiles
  __shared__ __align__(16) unsigned short bufB[128 * 136];   // 128-ch tiles

  const int t = threadIdx.x;
  const int node0 = blockIdx.x * 128;
  const int lane = t & 63;
  const int w  = t >> 6;
  const int wr = w >> 1, wc = w & 1;
  const int l16 = lane & 15, kg = lane >> 4;

  // ---- stage x (5ch fp32) + W1/b1 into bufB head (dead space pre-t2) ----
  float* sxs = (float*)bufB;          // 640 floats
  float* sw1 = (float*)bufB + 640;    // 320 floats (W1) + 64 (b1) contiguous
  {
    const long gbase = (long)node0 * F_;
    for (int i = t; i < 128 * F_; i += 256) {
      const long g = gbase + i;
      sxs[i] = (g < (long)N_ * F_) ? x[g] : 0.f;
    }
    for (int i = t; i < 384; i += 256)
      sw1[i] = (i < 320) ? pW1[i] : pb1[i - 320];
  }
  __syncthreads();

  // ---- stage1: t1 = relu(x@W1+b1) -> bufA (VALU, K=5) ----
  {
    const int n = t >> 1;
    const int half = (t & 1) * 32;
    float xr[F_];
    #pragma unroll
    for (int k = 0; k < F_; ++k) xr[k] = sxs[n * F_ + k];
    const float* sb1 = sw1 + 320;
    #pragma unroll
    for (int q = 0; q < 8; ++q) {
      float o[4];
      #pragma unroll
      for (int jj = 0; jj < 4; ++jj) {
        const int f = half + q * 4 + jj;
        float a = sb1[f];
        #pragma unroll
        for (int k = 0; k < F_; ++k) a = fmaf(xr[k], sw1[k * 64 + f], a);
        o[jj] = fmaxf(a, 0.f);
      }
      uint2 pkd;
      pkd.x = pk2(o[0], o[1]);
      pkd.y = pk2(o[2], o[3]);
      *(uint2*)&bufA[n * 72 + half + q * 4] = pkd;
    }
  }
  __syncthreads();

  f32x4 acc[4][4];

  // ---- stage2: t2 = relu(t1@W2+b2) : K=64 -> M=128, result to bufB ----
  gemm_frag<64, 128>(bufA, wt_p2, acc, wr, wc, l16, kg);
  acc_to_lds<128, true, 136>(bufB, acc, pb2, wr, wc, l16, kg);  // sxs dead
  __syncthreads();

  // ---- stage3: h = t2@W3+b3 : K=128 -> M=128, overwrite bufB ----
  gemm_frag<128, 128>(bufB, wt_p3, acc, wr, wc, l16, kg);
  __syncthreads();                      // all reads of t2 complete
  acc_to_lds<128, false, 136>(bufB, acc, pb3, wr, wc, l16, kg);
  __syncthreads();

  // ---- projections: q,k,v (bf16) ----
  {
    const unsigned short* wtsP[3] = {wt_q, wt_k, wt_v};
    const float* bsP[3] = {qb, kb, vb};
    unsigned short* ysP[3] = {q16, k16, v16};
    #pragma unroll
    for (int ws = 0; ws < 3; ++ws) {
      gemm_frag<128, 128>(bufB, wtsP[ws], acc, wr, wc, l16, kg);
      const float* __restrict__ bias = bsP[ws];
      unsigned short* __restrict__ Yb = ysP[ws];
      float4 b4[4];
      #pragma unroll
      for (int i = 0; i < 4; ++i)
        b4[i] = *(const float4*)&bias[(wr * 4 + i) * 16 + kg * 4];
      #pragma unroll
      for (int j = 0; j < 4; ++j) {
        const int node = node0 + wc * 64 + j * 16 + l16;
        if (node >= N_) continue;
        #pragma unroll
        for (int i = 0; i < 4; ++i) {
          const int f0 = (wr * 4 + i) * 16 + kg * 4;
          uint2 ob;
          ob.x = pk2(acc[i][j][0] + b4[i].x, acc[i][j][1] + b4[i].y);
          ob.y = pk2(acc[i][j][2] + b4[i].z, acc[i][j][3] + b4[i].w);
          *(uint2*)&Yb[(long)node * D_ + f0] = ob;
        }
      }
    }
  }

  // ---- skip projection (fp32 into out) ----
  gemm_frag<128, 128>(bufB, wt_s, acc, wr, wc, l16, kg);
  {
    float4 b4[4];
    #pragma unroll
    for (int i = 0; i < 4; ++i)
      b4[i] = *(const float4*)&sb[(wr * 4 + i) * 16 + kg * 4];
    #pragma unroll
    for (int j = 0; j < 4; ++j) {
      const int node = node0 + wc * 64 + j * 16 + l16;
      if (node >= N_) continue;
      #pragma unroll
      for (int i = 0; i < 4; ++i) {
        const int f0 = (wr * 4 + i) * 16 + kg * 4;
        float4 o = make_float4(acc[i][j][0] + b4[i].x, acc[i][j][1] + b4[i].y,
                               acc[i][j][2] + b4[i].z, acc[i][j][3] + b4[i].w);
        *(float4*)&out[(long)node * D_ + f0] = o;
      }
    }
  }
}

// ---------------------------------------------------------------------------
// Fused update MLP with residual: out = out + mlp(out). Intermediates in LDS.
// ---------------------------------------------------------------------------
__global__ __launch_bounds__(256) void k_update(
    const unsigned short* __restrict__ wt_u1, const float* __restrict__ ub1,
    const unsigned short* __restrict__ wt_u2, const float* __restrict__ ub2,
    const unsigned short* __restrict__ wt_u3, const float* __restrict__ ub3,
    float* __restrict__ out)
{
  __shared__ __align__(16) unsigned short bufA[128 * 72];
  __shared__ __align__(16) unsigned short bufB[128 * 136];

  const int t = threadIdx.x;
  const int node0 = blockIdx.x * 128;
  const int lane = t & 63;
  const int w  = t >> 6;
  const int wr = w >> 1, wc = w & 1;
  const int l16 = lane & 15, kg = lane >> 4;

  // ---- stage h (fp32 out) -> bf16 bufB ----
  #pragma unroll
  for (int i = 0; i < 16; ++i) {
    const int g = t + 256 * i;
    const int row = g >> 5;          // 32 float4 per row
    const int kc  = g & 31;
    const int node = node0 + row;
    float4 xv = (node < N_) ? ((const float4*)out)[(long)node * 32 + kc]
                            : make_float4(0.f, 0.f, 0.f, 0.f);
    uint2 p;
    p.x = pk2(xv.x, xv.y);
    p.y = pk2(xv.z, xv.w);
    *(uint2*)&bufB[row * 136 + kc * 4] = p;
  }
  __syncthreads();

  f32x4 acc[4][4];

  // ---- u1: K=128 -> M=64, relu, to bufA ----
  gemm_frag<128, 64>(bufB, wt_u1, acc, wr, wc, l16, kg);
  acc_to_lds<64, true, 72>(bufA, acc, ub1, wr, wc, l16, kg);
  __syncthreads();

  // ---- u2: K=64 -> M=128, relu, to bufB ----
  gemm_frag<64, 128>(bufA, wt_u2, acc, wr, wc, l16, kg);
  acc_to_lds<128, true, 136>(bufB, acc, ub2, wr, wc, l16, kg);
  __syncthreads();

  // ---- u3: K=128 -> M=128 + bias + residual(out) -> out ----
  gemm_frag<128, 128>(bufB, wt_u3, acc, wr, wc, l16, kg);
  {
    float4 b4[4];
    #pragma unroll
    for (int i = 0; i < 4; ++i)
      b4[i] = *(const float4*)&ub3[(wr * 4 + i) * 16 + kg * 4];
    #pragma unroll
    for (int j = 0; j < 4; ++j) {
      const int node = node0 + wc * 64 + j * 16 + l16;
      if (node >= N_) continue;
      #pragma unroll
      for (int i = 0; i < 4; ++i) {
        const int f0 = (wr * 4 + i) * 16 + kg * 4;
        const float4 r = *(const float4*)&out[(long)node * D_ + f0];
        float4 o = make_float4(acc[i][j][0] + b4[i].x + r.x,
                               acc[i][j][1] + b4[i].y + r.y,
                               acc[i][j][2] + b4[i].z + r.z,
                               acc[i][j][3] + b4[i].w + r.w);
        *(float4*)&out[(long)node * D_ + f0] = o;
      }
    }
  }
}

// ---------------------------------------------------------------------------
// CSR build: histogram -> scan (2 dispatches) -> fill
// ---------------------------------------------------------------------------
__global__ __launch_bounds__(256) void k_hist(const int* __restrict__ ei,
                                              int* __restrict__ deg) {
  int e = blockIdx.x * 256 + threadIdx.x;
  if (e < E_) atomicAdd(&deg[ei[E_ + e]], 1);
}

__global__ __launch_bounds__(256) void k_scan1(const int* __restrict__ deg,
                                               int* __restrict__ off,
                                               int* __restrict__ bsum) {
  __shared__ int s[256];
  const int t = threadIdx.x;
  const int i = blockIdx.x * 256 + t;
  const int v = (i < N_) ? deg[i] : 0;
  s[t] = v;
  __syncthreads();
  #pragma unroll
  for (int o = 1; o < 256; o <<= 1) {
    int u = (t >= o) ? s[t - o] : 0;
    __syncthreads();
    s[t] += u;
    __syncthreads();
  }
  if (i < N_) off[i] = s[t] - v;
  if (t == 255) bsum[blockIdx.x] = s[255];
}

// scan2 folded in: each block reduces its own prefix of bsum (<=391 ints, L2)
__global__ __launch_bounds__(256) void k_scan23(int* __restrict__ off,
                                                const int* __restrict__ bsum,
                                                int* __restrict__ cur) {
  __shared__ int sacc[256];
  const int t = threadIdx.x;
  const int bid = blockIdx.x;
  int s = 0;
  for (int j = t; j < bid; j += 256) s += bsum[j];
  sacc[t] = s;
  __syncthreads();
  #pragma unroll
  for (int o = 128; o > 0; o >>= 1) {
    if (t < o) sacc[t] += sacc[t + o];
    __syncthreads();
  }
  const int prefix = sacc[0];
  const int i = bid * 256 + t;
  if (i < N_) {
    const int o = off[i] + prefix;
    off[i] = o;
    cur[i] = o;
  }
}

__global__ __launch_bounds__(256) void k_fill(const int* __restrict__ ei,
                                              int* __restrict__ cur,
                                              int* __restrict__ esrc) {
  int e = blockIdx.x * 256 + threadIdx.x;
  if (e < E_) {
    int src = ei[e], dst = ei[E_ + e];
    int pos = atomicAdd(&cur[dst], 1);
    esrc[pos] = src;
  }
}

// ---------------------------------------------------------------------------
// Flash-style attention aggregation: one wave per destination node, split
// into two independent 32-lane halves. Lane owns 4 channels (uint2 loads);
// half h processes edges start+2p+h. 8-lane DPP reduce per head group.
// Index prefetch 2 deep, data prefetch 1 deep. Halves merged at the end.
// ---------------------------------------------------------------------------
__global__ __launch_bounds__(256) void k_attn(
    const int* __restrict__ esrc, const int* __restrict__ off,
    const int* __restrict__ deg,
    const unsigned short* __restrict__ q,
    const unsigned short* __restrict__ kbuf,
    const unsigned short* __restrict__ vbuf,
    float* __restrict__ out)
{
  const int node = blockIdx.x * 4 + (threadIdx.x >> 6);
  const int lane = threadIdx.x & 63;
  if (node >= N_) return;

  const int start = off[node];
  const int cnt   = deg[node];
  const int end   = start + cnt;
  const int h = lane >> 5;
  const int c = lane & 31;
  // scale * log2(e): scores land directly in exp2 domain
  const float C = 0.17677669529663687f * 1.4426950408889634f;

  const uint2 qu = *(const uint2*)&q[(long)node * D_ + 4 * c];
  const float2 q01 = bf2f2(qu.x), q23 = bf2f2(qu.y);
  const float qx0 = q01.x * C, qx1 = q01.y * C;
  const float qx2 = q23.x * C, qx3 = q23.y * C;

  float m = -__builtin_inff(), l = 0.f;
  float a0 = 0.f, a1 = 0.f, a2 = 0.f, a3 = 0.f;

  const int P = (cnt + 1) >> 1;
  if (P > 0) {
    int e = start + h;
    bool v_cur = e < end;
    int i_cur = esrc[v_cur ? e : start];
    const int e1 = e + 2;
    bool v_nxt = e1 < end;
    int i_nxt = esrc[v_nxt ? e1 : start];

    uint2 kc = *(const uint2*)&kbuf[(long)i_cur * D_ + 4 * c];
    uint2 vc = *(const uint2*)&vbuf[(long)i_cur * D_ + 4 * c];

    for (int p = 0; ; ++p) {
      const bool more = (p + 1) < P;
      uint2 kn, vn;
      int i_n2 = 0;
      bool v_n2 = false;
      if (more) {                        // prefetch: data p+1, index p+2
        kn = *(const uint2*)&kbuf[(long)i_nxt * D_ + 4 * c];
        vn = *(const uint2*)&vbuf[(long)i_nxt * D_ + 4 * c];
        const int e2 = start + 2 * (p + 2) + h;
        v_n2 = e2 < end;
        i_n2 = esrc[v_n2 ? e2 : start];
      }

      const float2 k01 = bf2f2(kc.x), k23 = bf2f2(kc.y);
      float ps = fmaf(qx0, k01.x, fmaf(qx1, k01.y, fmaf(qx2, k23.x, qx3 * k23.y)));
      ps = rowsum8(ps);
      ps = v_cur ? ps : -__builtin_inff();

      const float mn = fmaxf(m, ps);
      const float s  = __builtin_amdgcn_exp2f(fmaxf(m  - mn, -200.f));
      const float ee = __builtin_amdgcn_exp2f(fmaxf(ps - mn, -200.f));
      const float2 v01 = bf2f2(vc.x), v23 = bf2f2(vc.y);
      l  = fmaf(l,  s, ee);
      a0 = fmaf(a0, s, ee * v01.x);
      a1 = fmaf(a1, s, ee * v01.y);
      a2 = fmaf(a2, s, ee * v23.x);
      a3 = fmaf(a3, s, ee * v23.y);
      m = mn;

      if (!more) break;
      v_cur = v_nxt; kc = kn; vc = vn;
      v_nxt = v_n2;  i_nxt = i_n2;
    }
  }

  // ---- merge the two half-wave online-softmax states ----
  const float mB = __shfl_xor(m, 32);
  const float lB = __shfl_xor(l, 32);
  const float b0 = __shfl_xor(a0, 32);
  const float b1 = __shfl_xor(a1, 32);
  const float b2 = __shfl_xor(a2, 32);
  const float b3 = __shfl_xor(a3, 32);

  const float mm = fmaxf(m, mB);
  const float sA = __builtin_amdgcn_exp2f(fmaxf(m  - mm, -200.f));
  const float sB = __builtin_amdgcn_exp2f(fmaxf(mB - mm, -200.f));
  const float L  = fmaf(l, sA, lB * sB);

  if (h == 0 && L > 0.f) {
    const float inv = 1.0f / L;
    float4* op = (float4*)&out[(long)node * D_ + 4 * c];
    float4 cv = *op;
    cv.x += fmaf(a0, sA, b0 * sB) * inv;
    cv.y += fmaf(a1, sA, b1 * sB) * inv;
    cv.z += fmaf(a2, sA, b2 * sB) * inv;
    cv.w += fmaf(a3, sA, b3 * sB) * inv;
    *op = cv;
  }
}

// ---------------------------------------------------------------------------
extern "C" void kernel_launch(void* const* d_in, const int* in_sizes, int n_in,
                              void* d_out, int out_size, void* d_ws, size_t ws_size,
                              hipStream_t stream) {
  const float* x   = (const float*)d_in[0];
  const int*   ei  = (const int*)d_in[1];
  const float* pW1 = (const float*)d_in[2];  const float* pb1 = (const float*)d_in[3];
  const float* pW2 = (const float*)d_in[4];  const float* pb2 = (const float*)d_in[5];
  const float* pW3 = (const float*)d_in[6];  const float* pb3 = (const float*)d_in[7];
  const float* uW1 = (const float*)d_in[8];  const float* ub1 = (const float*)d_in[9];
  const float* uW2 = (const float*)d_in[10]; const float* ub2 = (const float*)d_in[11];
  const float* uW3 = (const float*)d_in[12]; const float* ub3 = (const float*)d_in[13];
  const float* qW  = (const float*)d_in[14]; const float* qb  = (const float*)d_in[15];
  const float* kW  = (const float*)d_in[16]; const float* kb  = (const float*)d_in[17];
  const float* vW  = (const float*)d_in[18]; const float* vb  = (const float*)d_in[19];
  const float* sW  = (const float*)d_in[20]; const float* sb  = (const float*)d_in[21];

  float* out = (float*)d_out;
  float* ws  = (float*)d_ws;

  const long ND = (long)N_ * D_;
  // regions (ND floats each): 0=CSR overlay, 1=q, 2=k, 3=v; 4=weights
  unsigned short* q16 = (unsigned short*)(ws + ND);
  unsigned short* k16 = (unsigned short*)(ws + 2 * ND);
  unsigned short* v16 = (unsigned short*)(ws + 3 * ND);

  unsigned short* wtb = (unsigned short*)(ws + 4 * ND);
  unsigned short* wt_p2 = wtb;            // 64x128
  unsigned short* wt_p3 = wtb + 8192;     // 128x128
  unsigned short* wt_q  = wtb + 24576;
  unsigned short* wt_k  = wtb + 40960;
  unsigned short* wt_v  = wtb + 57344;
  unsigned short* wt_s  = wtb + 73728;
  unsigned short* wt_u1 = wtb + 90112;    // 128x64
  unsigned short* wt_u2 = wtb + 98304;    // 64x128
  unsigned short* wt_u3 = wtb + 106496;   // 128x128

  // CSR overlays in region 0
  int* deg  = (int*)ws;
  int* off  = deg + N_;
  int* cur  = off + N_;
  int* esrc = cur + N_;
  int* bsum = esrc + E_;

  const int gT = (N_ + 127) / 128;    // 782

  // --- weight conversion + deg zeroing (one dispatch) ---
  k_wconv_all<<<WCONV_NB + SCAN_NB, 256, 0, stream>>>(
      pW2, pW3, qW, kW, vW, sW, uW1, uW2, uW3, wtb, deg);

  // --- CSR build ---
  k_hist  <<<(E_ + 255) / 256, 256, 0, stream>>>(ei, deg);
  k_scan1 <<<SCAN_NB, 256, 0, stream>>>(deg, off, bsum);
  k_scan23<<<SCAN_NB, 256, 0, stream>>>(off, bsum, cur);
  k_fill  <<<(E_ + 255) / 256, 256, 0, stream>>>(ei, cur, esrc);

  // --- fused prep MLP + projections: x -> q,k,v (bf16) + skip (fp32 in out) ---
  k_prep_proj<<<gT, 256, 0, stream>>>(
      x, pW1, pb1, wt_p2, pb2, wt_p3, pb3,
      wt_q, qb, wt_k, kb, wt_v, vb, wt_s, sb,
      q16, k16, v16, out);

  // --- attention (adds onto skip already in out) ---
  k_attn<<<(N_ + 3) / 4, 256, 0, stream>>>(esrc, off, deg, q16, k16, v16, out);

  // --- fused update MLP with residual: out = out + mlp(out) ---
  k_update<<<gT, 256, 0, stream>>>(wt_u1, ub1, wt_u2, ub2, wt_u3, ub3, out);
}